// Round 4
// baseline (235.390 us; speedup 1.0000x reference)
//
#include <hip/hip_runtime.h>

#define BB 64
#define CC 128
#define TT 4096
#define NN 6            // KNOT + 2
#define HH 819.0f       // (T-1)/(KNOT+1) = 4095/5, exact in fp32
#define NTHR 512
#define EPT 8           // curve elements per thread (NTHR*EPT == TT)
#define NWAVE (NTHR / 64)
#define NROW (BB * CC)
#define NSPAN 5
#define TABBYTES ((size_t)NROW * NSPAN * 16)

typedef float f4 __attribute__((ext_vector_type(4)));

__device__ __forceinline__ void nt_store4(float* p, f4 v) {
    __builtin_nontemporal_store(v, (f4*)p);
}

// LDS pad: +1 float per 32 breaks power-of-2 stride conflicts.
__device__ __forceinline__ int padi(int j) { return j + (j >> 5); }

// ---- 6x6 not-a-knot solve; A compile-time constant -> multipliers fold ----
__device__ __forceinline__ void spline_solve(const float* __restrict__ yy,
                                             int b, int c, float* y, float* Mv)
{
    #pragma unroll
    for (int k = 0; k < NN; ++k)
        y[k] = yy[((size_t)b * NN + k) * CC + c];
    float Aug[NN][NN + 1];
    #pragma unroll
    for (int i = 0; i < NN; ++i)
        #pragma unroll
        for (int j = 0; j < NN + 1; ++j)
            Aug[i][j] = 0.0f;
    Aug[0][0] = 1.0f;  Aug[0][1] = -2.0f;  Aug[0][2] = 1.0f;
    Aug[5][3] = 1.0f;  Aug[5][4] = -2.0f;  Aug[5][5] = 1.0f;
    #pragma unroll
    for (int i = 1; i < NN - 1; ++i) {
        Aug[i][i - 1] = HH / 6.0f;
        Aug[i][i]     = 2.0f * HH / 3.0f;
        Aug[i][i + 1] = HH / 6.0f;
        Aug[i][NN]    = (y[i + 1] - 2.0f * y[i] + y[i - 1]) / HH;
    }
    #pragma unroll
    for (int k = 0; k < NN; ++k) {
        float inv = 1.0f / Aug[k][k];
        #pragma unroll
        for (int i = k + 1; i < NN; ++i) {
            float m = Aug[i][k] * inv;
            #pragma unroll
            for (int j = k; j < NN + 1; ++j)
                Aug[i][j] -= m * Aug[k][j];
        }
    }
    #pragma unroll
    for (int i = NN - 1; i >= 0; --i) {
        float s = Aug[i][NN];
        #pragma unroll
        for (int j = i + 1; j < NN; ++j)
            s -= Aug[i][j] * Mv[j];
        Mv[i] = s / Aug[i][i];
    }
}

// ---- setup: per-(row, span) Horner coeffs (a,b,c,d) into workspace ----
// curve(s) = a + s*(b + s*(c + s*d)), s = t - span*HH
__global__ __launch_bounds__(256) void spline_coef_kernel(
    const float* __restrict__ yy, f4* __restrict__ tab)
{
    const int row = blockIdx.x * 256 + threadIdx.x;   // 8192 rows, coalesced in c
    const int b = row / CC;
    const int c = row % CC;
    float y[NN], Mv[NN];
    spline_solve(yy, b, c, y, Mv);
    const float invh  = 1.0f / HH;
    const float inv6h = 1.0f / (6.0f * HH);
    #pragma unroll
    for (int s = 0; s < NSPAN; ++s) {
        f4 cf;
        cf.x = y[s];
        cf.y = (y[s + 1] - y[s]) * invh - Mv[s] * (HH / 3.0f) - Mv[s + 1] * (HH / 6.0f);
        cf.z = Mv[s] * 0.5f;
        cf.w = (Mv[s + 1] - Mv[s]) * inv6h;
        tab[row * NSPAN + s] = cf;
    }
}

// ============================ main kernel ==================================
// TABLE=1: coeffs from workspace table. TABLE=0: in-kernel solve (fallback).
template <int TABLE>
__global__ __launch_bounds__(NTHR) void timewarp_kernel(
    const float* __restrict__ x,
    const float* __restrict__ yy,
    const float* __restrict__ mask_rand,
    const f4* __restrict__ tab,
    float* __restrict__ out)
{
    const int row = blockIdx.x;          // b*C + c
    const int b   = row / CC;
    const int tid = threadIdx.x;

    const float* xrow = x + (size_t)row * TT;
    float* orow       = out + (size_t)row * TT;

    // mask_rand >= 0.5 -> bit-exact copy (uniform per block)
    if (!(mask_rand[b] < 0.5f)) {
        const f4* xi = (const f4*)xrow;
        nt_store4(orow + 4 * tid,          xi[tid]);
        nt_store4(orow + 4 * (tid + NTHR), xi[tid + NTHR]);
        return;
    }

    __shared__ float sh_res[TT + TT / 32];   // final values, padded scatter target
    __shared__ float sh_xx[NTHR];            // xp boundary exchange (bit-exact)
    __shared__ float sh_wsum[NWAVE];         // per-wave scan totals

    // ---- loads issued up front: x row chunk + this thread's 2 coeff sets ----
    const int t0 = tid * EPT;
    int idxA = t0 / 819;  if (idxA > 4) idxA = 4;
    int idxB = idxA + 1;  if (idxB > 4) idxB = 4;

    const f4 v0 = *(const f4*)(xrow + t0);
    const f4 v1 = *(const f4*)(xrow + t0 + 4);
    // neighbor's first fp value, bit-identical from global (L1-hot); unused for tid 511
    const float fpb = xrow[(t0 + EPT < TT) ? (t0 + EPT) : (TT - 1)];

    f4 cfA, cfB;
    if (TABLE) {
        cfA = tab[row * NSPAN + idxA];       // lanes share spans -> ~2 lines/wave
        cfB = tab[row * NSPAN + idxB];
    } else {
        const int c = row % CC;
        float y[NN], Mv[NN];
        spline_solve(yy, b, c, y, Mv);
        const float invh  = 1.0f / HH;
        const float inv6h = 1.0f / (6.0f * HH);
        float MiA = Mv[0], Mi1A = Mv[1], yiA = y[0], yi1A = y[1];
        #pragma unroll
        for (int s = 1; s <= 4; ++s)
            if (idxA >= s) { MiA = Mv[s]; Mi1A = Mv[s + 1]; yiA = y[s]; yi1A = y[s + 1]; }
        float MiB = Mv[0], Mi1B = Mv[1], yiB = y[0], yi1B = y[1];
        #pragma unroll
        for (int s = 1; s <= 4; ++s)
            if (idxB >= s) { MiB = Mv[s]; Mi1B = Mv[s + 1]; yiB = y[s]; yi1B = y[s + 1]; }
        cfA.x = yiA;
        cfA.y = (yi1A - yiA) * invh - MiA * (HH / 3.0f) - Mi1A * (HH / 6.0f);
        cfA.z = MiA * 0.5f;
        cfA.w = (Mi1A - MiA) * inv6h;
        cfB.x = yiB;
        cfB.y = (yi1B - yiB) * invh - MiB * (HH / 3.0f) - Mi1B * (HH / 6.0f);
        cfB.z = MiB * 0.5f;
        cfB.w = (Mi1B - MiB) * inv6h;
    }

    float fpv[EPT];
    fpv[0] = v0.x; fpv[1] = v0.y; fpv[2] = v0.z; fpv[3] = v0.w;
    fpv[4] = v1.x; fpv[5] = v1.y; fpv[6] = v1.z; fpv[7] = v1.w;

    const float xlA = (float)idxA * HH;
    const float xlB = (float)idxB * HH;
    const float tb  = (float)((idxA + 1) * 819);   // first t belonging to span B

    // ---- curve + thread-local inclusive scan ----
    float loc[EPT];
    float running = 0.0f;
    #pragma unroll
    for (int k = 0; k < EPT; ++k) {
        float ft = (float)(t0 + k);
        bool inB = ft >= tb;
        f4    cf = inB ? cfB : cfA;
        float xl = inB ? xlB : xlA;
        float s  = ft - xl;
        running += fmaf(s, fmaf(s, fmaf(s, cf.w, cf.z), cf.y), cf.x);
        loc[k] = running;
    }

    // ---- wave scan (shfl) + cross-wave fixup (barrier 1) ----
    const int lane = tid & 63, wid = tid >> 6;
    float ws = running;
    #pragma unroll
    for (int d = 1; d < 64; d <<= 1) {
        float v = __shfl_up(ws, d, 64);
        if (lane >= d) ws += v;
    }
    if (lane == 63) sh_wsum[wid] = ws;
    __syncthreads();                            // B1
    float wo = 0.0f, total = 0.0f;
    #pragma unroll
    for (int w = 0; w < NWAVE; ++w) {
        float s = sh_wsum[w];
        total += s;
        if (w < wid) wo += s;
    }
    const float offs  = wo + (ws - running);    // exclusive prefix of this thread
    const float scale = 4095.0f / total;        // tt * (T-1) / tt_last

    float xpv[EPT + 1];
    #pragma unroll
    for (int k = 0; k < EPT; ++k)
        xpv[k] = (loc[k] + offs) * scale;
    sh_xx[tid] = xpv[0];
    __syncthreads();                            // B2: boundaries visible, bit-exact
    xpv[EPT] = (tid < NTHR - 1) ? sh_xx[tid + 1] : 4095.0f;  // tid 511: unused

    // ---- direct forward scatter of final values ----
    // segment j owns q in [ceil(xp[j]), ceil(xp[j+1])-1]; boundaries shared
    // bit-exactly via sh_xx -> telescoping coverage, no gaps, avg 1 q/segment.
    #pragma unroll
    for (int k = 0; k < EPT; ++k) {
        const int seg = t0 + k;
        if (seg < TT - 1) {
            float xa = xpv[k], xb = xpv[k + 1];
            float fa = fpv[k];
            float fb = (k < EPT - 1) ? fpv[k + 1] : fpb;
            float d  = xb - xa;
            float slope = (d > 0.0f) ? (fb - fa) * __builtin_amdgcn_rcpf(d) : 0.0f;
            float a0 = fmaf(-xa, slope, fa);
            int qlo = (int)ceilf(xa);  if (qlo < 0) qlo = 0;
            int qhi = (int)ceilf(xb);  if (qhi > TT) qhi = TT;
            for (int q = qlo; q < qhi; ++q)
                sh_res[padi(q)] = fmaf((float)q, slope, a0);
        }
    }
    if (tid == 0) {                             // head: q < xp[0] -> fp[0]
        int q1 = (int)ceilf(xpv[0]);  if (q1 > TT) q1 = TT;
        for (int q = 0; q < q1; ++q) sh_res[padi(q)] = fpv[0];
    }
    if (tid == NTHR - 1) {                      // tail: q >= xp[4095] -> fp[4095]
        int q0 = (int)ceilf(xpv[EPT - 1]);  if (q0 < 0) q0 = 0;
        for (int q = q0; q < TT; ++q) sh_res[padi(q)] = fpv[EPT - 1];
    }
    __syncthreads();                            // B3: sh_res complete

    // ---- restage: coalesced nontemporal float4 stores ----
    #pragma unroll
    for (int kk = 0; kk < 2; ++kk) {
        int i4 = tid + NTHR * kk;
        int fb4 = 4 * i4;
        int p  = padi(fb4);
        f4 v;
        v.x = sh_res[p + 0];
        v.y = sh_res[p + 1];
        v.z = sh_res[p + 2];
        v.w = sh_res[p + 3];
        nt_store4(orow + fb4, v);
    }
}

extern "C" void kernel_launch(void* const* d_in, const int* in_sizes, int n_in,
                              void* d_out, int out_size, void* d_ws, size_t ws_size,
                              hipStream_t stream) {
    const float* x    = (const float*)d_in[0];   // (64,128,4096) fp32
    const float* yy   = (const float*)d_in[1];   // (64,6,128)    fp32
    const float* mask = (const float*)d_in[2];   // (64,1,1)      fp32
    float* out = (float*)d_out;                  // (64,128,4096) fp32

    if (d_ws != nullptr && ws_size >= TABBYTES) {
        f4* tab = (f4*)d_ws;
        spline_coef_kernel<<<dim3(NROW / 256), dim3(256), 0, stream>>>(yy, tab);
        timewarp_kernel<1><<<dim3(NROW), dim3(NTHR), 0, stream>>>(x, yy, mask, tab, out);
    } else {
        timewarp_kernel<0><<<dim3(NROW), dim3(NTHR), 0, stream>>>(x, yy, mask, nullptr, out);
    }
}